// Round 13
// baseline (338.701 us; speedup 1.0000x reference)
//
#include <hip/hip_runtime.h>
#include <math.h>

// GQA B=1 S=2048 D=128 H=32 KVH=8. d_out f32.
// Round 13: swapped QK^T via 32x32x16 MFMA (S^T = K x Q, Q in registers) ->
// softmax lane-local, P redistributed to PV B-frag with cvt_pk_bf16 +
// permlane32_swap (T12). No LDS for P or O. KVBLK=64, K rows 4-bit-XOR
// swizzled (2-way), r11's 1-barrier/tile loop (r12's counted-vmcnt regressed).

#define SCALE_L2E 0.12751878222550723f   // (1/sqrt(128)) * log2(e)
#define L2_10K_64 0.20762050593045952f   // log2(10000)/64

typedef short bf16x8 __attribute__((ext_vector_type(8)));
typedef float f32x4 __attribute__((ext_vector_type(4)));
typedef float f32x16 __attribute__((ext_vector_type(16)));

__device__ __forceinline__ unsigned short f2b(float f) {
  union { float f; unsigned u; } x; x.f = f;
  return (unsigned short)((x.u + 0x7FFFu + ((x.u >> 16) & 1u)) >> 16);
}
__device__ __forceinline__ float b2f(unsigned short b) {
  union { unsigned u; float f; } x; x.u = ((unsigned)b) << 16;
  return x.f;
}
__device__ __forceinline__ void lds_dma16(void* lds, const void* g) {
  __builtin_amdgcn_global_load_lds(
      (const __attribute__((address_space(1))) unsigned int*)g,
      (__attribute__((address_space(3))) unsigned int*)lds, 16, 0, 0);
}
__device__ __forceinline__ unsigned cvtpk(float lo, float hi) {
  unsigned r;
  asm("v_cvt_pk_bf16_f32 %0, %1, %2" : "=v"(r) : "v"(lo), "v"(hi));
  return r;
}
// after swap: a=[a_lo | b_lo], b=[a_hi | b_hi]  (lanes0-31 | lanes32-63)
#define PLSWAP(a, b) asm("v_permlane32_swap_b32 %0, %1" : "+v"(a), "+v"(b))

// redistribute 8 packed u32 (C-layout kv pairs) into two B-frags (k-groups)
__device__ __forceinline__ void redist(unsigned pw[8], bf16x8* f0, bf16x8* f1) {
  PLSWAP(pw[0], pw[2]); PLSWAP(pw[1], pw[3]);
  PLSWAP(pw[4], pw[6]); PLSWAP(pw[5], pw[7]);
  union { unsigned u[4]; bf16x8 v; } a, b;
  a.u[0] = pw[0]; a.u[1] = pw[1]; a.u[2] = pw[2]; a.u[3] = pw[3];
  b.u[0] = pw[4]; b.u[1] = pw[5]; b.u[2] = pw[6]; b.u[3] = pw[7];
  *f0 = a.v; *f1 = b.v;
}

// ---- weight prep (r12, unchanged) ----
__global__ __launch_bounds__(256) void prep_weights(
    const float* __restrict__ Wk, const float* __restrict__ Wv,
    const float* __restrict__ Wo, const float* __restrict__ Wq,
    const float* __restrict__ bo,
    unsigned short* __restrict__ Wkt, unsigned short* __restrict__ Wvt,
    unsigned short* __restrict__ Wot, unsigned short* __restrict__ Wq2,
    float* __restrict__ out, int big) {
  __shared__ unsigned short T[64][66];
  int b = blockIdx.x, tid = threadIdx.x;
  const float* W;
  unsigned short* D;
  int K, N, tk, tn;
  if (b < 32) {
    W = Wk; D = Wkt; K = 128; N = 1024; int ti = b;       tk = ti & 1;  tn = ti >> 1;
  } else if (b < 64) {
    W = Wv; D = Wvt; K = 128; N = 1024; int ti = b - 32;  tk = ti & 1;  tn = ti >> 1;
  } else if (b < 192) {
    W = Wo; D = Wot; K = 4096; N = 128; int ti = b - 64;  tk = ti >> 1; tn = ti & 1;
  } else if (b < 320) {
    if (!big) {
      int i0 = ((b - 192) * 256 + tid) * 16;
#pragma unroll
      for (int j = 0; j < 16; ++j) Wq2[i0 + j] = f2b(Wq[i0 + j]);
      return;
    }
    W = Wq; D = Wq2; K = 128; N = 4096; int ti = b - 192; tk = ti & 1;  tn = ti >> 1;
  } else {
    int i0 = ((b - 320) * 256 + tid) * 16;
#pragma unroll
    for (int j = 0; j < 16; ++j) out[i0 + j] = bo[(i0 + j) & 127];
    return;
  }
  int k0 = tk * 64, n0 = tn * 64;
  int c = tid & 63, q = tid >> 6;
#pragma unroll
  for (int i = 0; i < 16; ++i) {
    int r = i * 4 + q;
    T[r][c] = f2b(W[(size_t)(k0 + r) * N + n0 + c]);
  }
  __syncthreads();
#pragma unroll
  for (int i = 0; i < 16; ++i) {
    int r = i * 4 + q;
    D[(size_t)(n0 + r) * K + k0 + c] = T[c][r];
  }
}

// ---- projections (r12, unchanged): K->(g,t,d) RoPE'd; V->(g,d,t) RoPE'd
// honoring view scramble; Q (big) -> descrambled (H,S,D) ----
__global__ __launch_bounds__(256) void proj_all(
    const float* __restrict__ keys, const float* __restrict__ values,
    const float* __restrict__ query,
    const unsigned short* __restrict__ Wkt, const unsigned short* __restrict__ Wvt,
    const unsigned short* __restrict__ Wqt,
    const float* __restrict__ bk, const float* __restrict__ bv, const float* __restrict__ bq,
    unsigned short* __restrict__ kp, unsigned short* __restrict__ vt,
    unsigned short* __restrict__ qp) {
  int bx = blockIdx.x, m0 = blockIdx.y * 64;
  int tid = threadIdx.x;
  int w = tid >> 6, l = tid & 63;
  int l16 = l & 15, g4 = l >> 4;
  int arow = m0 + w * 16 + l16;
  const f32x4 fz = {0.f, 0.f, 0.f, 0.f};

  if (bx >= 16) {  // Q
    int n0 = (bx - 16) * 64;
    f32x4 acc[4];
#pragma unroll
    for (int nb = 0; nb < 4; ++nb) acc[nb] = fz;
#pragma unroll
    for (int kc = 0; kc < 4; ++kc) {
      int kbase = kc * 32 + g4 * 8;
      const float* xp = query + (size_t)arow * 128 + kbase;
      bf16x8 a;
#pragma unroll
      for (int j = 0; j < 8; ++j) a[j] = (short)f2b(xp[j]);
#pragma unroll
      for (int nb = 0; nb < 4; ++nb) {
        bf16x8 b = *(const bf16x8*)(Wqt + (size_t)(n0 + nb * 16 + l16) * 128 + kbase);
        acc[nb] = __builtin_amdgcn_mfma_f32_16x16x32_bf16(a, b, acc[nb], 0, 0, 0);
      }
    }
#pragma unroll
    for (int nb = 0; nb < 4; ++nb) {
      int n = n0 + nb * 16 + l16;
      float bvv = bq[n];
#pragma unroll
      for (int r = 0; r < 4; ++r) {
        int mi = m0 + w * 16 + g4 * 4 + r;
        int h = mi >> 6;
        int s = ((mi & 63) << 5) | (n >> 7);
        qp[((size_t)h * 2048 + s) * 128 + (n & 127)] = f2b(acc[nb][r] + bvv);
      }
    }
    return;
  }

  int vmode = bx >> 3;
  int n0 = (bx & 7) * 128, tb = bx & 7;
  const float* X = vmode ? values : keys;
  const unsigned short* Wt = vmode ? Wvt : Wkt;
  const float* bias = vmode ? bv : bk;
  f32x4 acc[8];
#pragma unroll
  for (int nb = 0; nb < 8; ++nb) acc[nb] = fz;
#pragma unroll
  for (int kc = 0; kc < 4; ++kc) {
    int kbase = kc * 32 + g4 * 8;
    const float* xp = X + (size_t)arow * 128 + kbase;
    bf16x8 a;
#pragma unroll
    for (int j = 0; j < 8; ++j) a[j] = (short)f2b(xp[j]);
#pragma unroll
    for (int nb = 0; nb < 8; ++nb) {
      bf16x8 b = *(const bf16x8*)(Wt + (size_t)(n0 + nb * 16 + l16) * 128 + kbase);
      acc[nb] = __builtin_amdgcn_mfma_f32_16x16x32_bf16(a, b, acc[nb], 0, 0, 0);
    }
  }
#pragma unroll
  for (int nb = 0; nb < 4; ++nb) {
    int d2 = nb * 16 + l16;
    float invf = exp2f(-(float)d2 * L2_10K_64);
    float blo = bias[n0 + d2], bhi = bias[n0 + d2 + 64];
#pragma unroll
    for (int r = 0; r < 4; ++r) {
      int mi = m0 + w * 16 + g4 * 4 + r;
      int t = (mi & 255) * 8 + tb;
      float ang = (float)t * invf;
      float sf, cf;
      __sincosf(ang, &sf, &cf);
      float x1 = acc[nb][r] + blo;
      float x2 = acc[nb + 4][r] + bhi;
      unsigned short lo = f2b(x1 * cf - x2 * sf);
      unsigned short hi = f2b(x2 * cf + x1 * sf);
      int g = mi >> 8;
      if (vmode) {
        vt[(size_t)g * 262144 + (size_t)d2 * 2048 + t] = lo;
        vt[(size_t)g * 262144 + (size_t)(d2 + 64) * 2048 + t] = hi;
      } else {
        kp[(size_t)g * 262144 + (size_t)t * 128 + d2] = lo;
        kp[(size_t)g * 262144 + (size_t)t * 128 + d2 + 64] = hi;
      }
    }
  }
}

__global__ void ws_marker(float* __restrict__ out) {
  out[blockIdx.x * 256 + threadIdx.x] = 12345.0f;
}

// QBLK=128 (4 waves x 32 q), KVBLK=64, grid 512 (2 blocks/CU).
// LDS: K[2][64][128]sh (2x16KB, 4-bit row-XOR chunk swizzle) @0
//      V^T[2][128][64]sh (2x16KB, 3-bit row-XOR) @32768.  total 64KB. No P/O LDS.
template <int FUSED_Q>
__global__ __launch_bounds__(256, 2) void attn_kernel(
    const float* __restrict__ X, const unsigned short* __restrict__ Wqb,
    const float* __restrict__ bq, const unsigned short* __restrict__ qp,
    const unsigned short* __restrict__ kp, const unsigned short* __restrict__ vt,
    const unsigned short* __restrict__ Wot, float* __restrict__ out) {
  __shared__ __align__(16) char smem[65536];
  int bid = blockIdx.x;
  int h = bid & 31, g = h & 7;
  int qi0 = (bid >> 5) * 128;
  int tid = threadIdx.x;
  int w = tid >> 6, l = tid & 63;
  int l31 = l & 31, hi = l >> 5;

  const f32x16 fz16 = {0.f};
  bf16x8 qfrag[8];  // B-operand: n=q=l31 (this wave's q = qi0+w*32+l31), k=d slice

  if (FUSED_Q) {
    unsigned short* Uni = (unsigned short*)smem;  // [4][4096]
    int r0 = h * 64 + (qi0 >> 5);
    int col0 = tid * 16;
#pragma unroll
    for (int jp = 0; jp < 2; ++jp) {
      float acc[2][16];
#pragma unroll
      for (int j = 0; j < 2; ++j)
#pragma unroll
        for (int cc = 0; cc < 16; ++cc) acc[j][cc] = bq[col0 + cc];
      const float* xr0 = X + (size_t)(r0 + jp * 2) * 128;
      const float* xr1 = xr0 + 128;
      for (int k = 0; k < 128; ++k) {
        float x0 = xr0[k], x1 = xr1[k];
        bf16x8 w0 = *(const bf16x8*)(Wqb + (size_t)k * 4096 + col0);
        bf16x8 w1 = *(const bf16x8*)(Wqb + (size_t)k * 4096 + col0 + 8);
#pragma unroll
        for (int e = 0; e < 8; ++e) {
          float f0 = b2f((unsigned short)w0[e]), f1 = b2f((unsigned short)w1[e]);
          acc[0][e] += x0 * f0; acc[0][8 + e] += x0 * f1;
          acc[1][e] += x1 * f0; acc[1][8 + e] += x1 * f1;
        }
      }
#pragma unroll
      for (int j = 0; j < 2; ++j)
#pragma unroll
        for (int cc = 0; cc < 16; ++cc)
          Uni[(jp * 2 + j) * 4096 + col0 + cc] = f2b(acc[j][cc]);
    }
    __syncthreads();
    int srow = w * 32 + l31;
    int sj = srow >> 5, scol = (srow & 31) * 128;
#pragma unroll
    for (int kc = 0; kc < 8; ++kc)
      qfrag[kc] = *(const bf16x8*)&Uni[sj * 4096 + scol + kc * 16 + hi * 8];
    __syncthreads();  // Uni reads done before DMA overwrites region
  } else {
    const unsigned short* qrow = qp + ((size_t)h * 2048 + qi0 + w * 32 + l31) * 128;
#pragma unroll
    for (int kc = 0; kc < 8; ++kc)
      qfrag[kc] = *(const bf16x8*)(qrow + kc * 16 + hi * 8);
  }

  const char* kg = (const char*)(kp + (size_t)g * 262144);
  const char* vg = (const char*)(vt + (size_t)g * 262144);

  // stage K tile tn (64 rows x 256B, 4-bit XOR chunk swizzle) into buf kb
#define STAGE_K(tn, kb)                                                         \
  {                                                                             \
    _Pragma("unroll") for (int i = 0; i < 4; ++i) {                             \
      int off = w * 4096 + i * 1024 + l * 16;                                   \
      int row = off >> 8, ch = (off >> 4) & 15;                                 \
      int rch = ch ^ (row & 15);                                                \
      lds_dma16(smem + (kb) * 16384 + w * 4096 + i * 1024,                      \
                kg + (size_t)(tn) * 16384 + (size_t)row * 256 + rch * 16);      \
    }                                                                           \
  }
  // stage V^T tile tn (128 rows x 128B, 3-bit XOR) into buf vb
#define STAGE_V(tn, vb)                                                         \
  {                                                                             \
    _Pragma("unroll") for (int i = 0; i < 4; ++i) {                             \
      int off = w * 4096 + i * 1024 + l * 16;                                   \
      int row = off >> 7, ch = (off >> 4) & 7;                                  \
      int rch = ch ^ (row & 7);                                                 \
      lds_dma16(smem + 32768 + (vb) * 16384 + w * 4096 + i * 1024,              \
                vg + (size_t)row * 4096 + (size_t)(tn) * 128 + rch * 16);       \
    }                                                                           \
  }

  STAGE_K(0, 0);
  STAGE_V(0, 0);
  __syncthreads();

  f32x16 oacc[4];  // O^T[d=db*32+rowpat][q=l31]
#pragma unroll
  for (int db = 0; db < 4; ++db) oacc[db] = fz16;
  float lacc = 0.f;

  int c = 0;
  for (int t = 0; t < 32; ++t) {
    if (t < 31) { STAGE_K(t + 1, c ^ 1); STAGE_V(t + 1, c ^ 1); }

    // QK^T swapped: S^T[kv][q] = K x Q, two 32-kv groups
#pragma unroll
    for (int jb = 0; jb < 2; ++jb) {
      f32x16 sacc = fz16;
      __builtin_amdgcn_s_setprio(1);
#pragma unroll
      for (int kc = 0; kc < 8; ++kc) {
        int row = jb * 32 + l31;
        int rch = (kc * 2 + hi) ^ (row & 15);
        bf16x8 kfrag = *(const bf16x8*)(smem + c * 16384 + row * 256 + rch * 16);
        sacc = __builtin_amdgcn_mfma_f32_32x32x16_bf16(kfrag, qfrag[kc], sacc, 0, 0, 0);
      }
      __builtin_amdgcn_s_setprio(0);
      // softmax: lane-local (lane owns q=l31; rows kv = (j&3)+8*(j>>2)+4*hi+32*jb)
      float p[16];
#pragma unroll
      for (int j = 0; j < 16; ++j) {
        p[j] = exp2f(sacc[j] * SCALE_L2E);
        lacc += p[j];
      }
      unsigned pw[8];
#pragma unroll
      for (int m = 0; m < 8; ++m) pw[m] = cvtpk(p[2 * m], p[2 * m + 1]);
      bf16x8 pf0, pf1;  // B-frags for k-groups kv [32jb, 32jb+16), [+16, +32)
      redist(pw, &pf0, &pf1);
      // PV: O^T[d][q] += V^T x P  (A=V^T: m=d, k=kv)
      __builtin_amdgcn_s_setprio(1);
#pragma unroll
      for (int ks = 0; ks < 2; ++ks) {
        int ksg = jb * 2 + ks;
        bf16x8 pf = ks ? pf1 : pf0;
#pragma unroll
        for (int db = 0; db < 4; ++db) {
          int row = db * 32 + l31;
          int rch = (ksg * 2 + hi) ^ (row & 7);
          bf16x8 vfrag = *(const bf16x8*)(smem + 32768 + c * 16384 + row * 128 + rch * 16);
          oacc[db] = __builtin_amdgcn_mfma_f32_32x32x16_bf16(vfrag, pf, oacc[db], 0, 0, 0);
        }
      }
      __builtin_amdgcn_s_setprio(0);
    }
    __syncthreads();  // reads of buf c done; prefetch DMA to c^1 drained
    c ^= 1;
  }

  // denominator: lane's lacc covers its hi-half of kv; one xor-32 completes
  float ltot = lacc + __shfl_xor(lacc, 32, 64);
  float invl = 1.f / ltot;

  // epilogue: out[q][no] += (O/l) @ Wo[h*128:+128][no], all in-register.
  // Redistribute O^T (k=d) exactly like P; A=Wo^T from global (L2-hot).
  f32x16 acc2[4];
#pragma unroll
  for (int nb = 0; nb < 4; ++nb) acc2[nb] = fz16;
  bf16x8 ofrag[8];
#pragma unroll
  for (int db = 0; db < 4; ++db) {
    unsigned pw[8];
#pragma unroll
    for (int m = 0; m < 8; ++m)
      pw[m] = cvtpk(oacc[db][2 * m] * invl, oacc[db][2 * m + 1] * invl);
    redist(pw, &ofrag[db * 2], &ofrag[db * 2 + 1]);
  }
#pragma unroll
  for (int ks = 0; ks < 8; ++ks) {
#pragma unroll
    for (int nb = 0; nb < 4; ++nb) {
      bf16x8 wof = *(const bf16x8*)(Wot + (size_t)(nb * 32 + l31) * 4096 + h * 128 + ks * 16 + hi * 8);
      acc2[nb] = __builtin_amdgcn_mfma_f32_32x32x16_bf16(wof, ofrag[ks], acc2[nb], 0, 0, 0);
    }
  }
  size_t qrow = (size_t)(qi0 + w * 32 + l31);
#pragma unroll
  for (int nb = 0; nb < 4; ++nb) {
#pragma unroll
    for (int j = 0; j < 16; ++j) {
      int no = nb * 32 + (j & 3) + 8 * (j >> 2) + 4 * hi;
      atomicAdd(&out[qrow * 128 + no], acc2[nb][j]);
    }
  }
#undef STAGE_K
#undef STAGE_V
}

extern "C" void kernel_launch(void* const* d_in, const int* in_sizes, int n_in,
                              void* d_out, int out_size, void* d_ws, size_t ws_size,
                              hipStream_t stream) {
  const float* query  = (const float*)d_in[0];
  const float* keys   = (const float*)d_in[1];
  const float* values = (const float*)d_in[2];
  const float* Wq = (const float*)d_in[3];
  const float* bq = (const float*)d_in[4];
  const float* Wk = (const float*)d_in[5];
  const float* bk = (const float*)d_in[6];
  const float* Wv = (const float*)d_in[7];
  const float* bv = (const float*)d_in[8];
  const float* Wo = (const float*)d_in[9];
  const float* bo = (const float*)d_in[10];
  float* out = (float*)d_out;
  char* ws = (char*)d_ws;
  const size_t MB = 1024 * 1024;
  if (ws_size < 10 * MB + 512 * 1024) {
    ws_marker<<<1024, 256, 0, stream>>>(out);
    return;
  }
  unsigned short* Wq2   = (unsigned short*)(ws);                        // 1 MiB
  unsigned short* Wkt   = (unsigned short*)(ws + 1 * MB);               // 256 KiB
  unsigned short* Wvt   = (unsigned short*)(ws + 1 * MB + 256 * 1024);  // 256 KiB
  unsigned short* Wot   = (unsigned short*)(ws + 1 * MB + 512 * 1024);  // 1 MiB
  unsigned short* kproj = (unsigned short*)(ws + 2 * MB + 512 * 1024);  // 4 MiB
  unsigned short* vt    = (unsigned short*)(ws + 6 * MB + 512 * 1024);  // 4 MiB
  unsigned short* qproj = (unsigned short*)(ws + 10 * MB + 512 * 1024); // 16 MiB (big)
  int big = ws_size >= 27 * MB;

  prep_weights<<<384, 256, 0, stream>>>(Wk, Wv, Wo, Wq, bo, Wkt, Wvt, Wot, Wq2, out, big);

  if (big) {
    proj_all<<<dim3(80, 32), 256, 0, stream>>>(keys, values, query, Wkt, Wvt, Wq2,
                                               bk, bv, bq, kproj, vt, qproj);
    attn_kernel<0><<<512, 256, 0, stream>>>(query, Wq2, bq, qproj, kproj, vt, Wot, out);
  } else {
    proj_all<<<dim3(16, 32), 256, 0, stream>>>(keys, values, query, Wkt, Wvt, Wq2,
                                               bk, bv, bq, kproj, vt, qproj);
    attn_kernel<1><<<512, 256, 0, stream>>>(query, Wq2, bq, nullptr, kproj, vt, Wot, out);
  }
}

// Round 14
// 171.488 us; speedup vs baseline: 1.9751x; 1.9751x over previous
//
#include <hip/hip_runtime.h>
#include <math.h>

// GQA B=1 S=2048 D=128 H=32 KVH=8. d_out f32.
// Round 14: kill the cross-XCD atomic storm (r13: 131MB atomic writes = the
// regression). Grid = (64 q-tiles of 32) x (8 g); the 4 waves of a block own
// heads {g,g+8,g+16,g+24} (same KV!). Epilogue: per-wave O@Wo partial ->
// LDS cross-wave sum -> PLAIN stores to part[g][q][no] (exclusive writer) ->
// tiny reduce over 8 g. Zero atomics. r13 swapped-QK^T loop kept verbatim.

#define SCALE_L2E 0.12751878222550723f   // (1/sqrt(128)) * log2(e)
#define L2_10K_64 0.20762050593045952f   // log2(10000)/64

typedef short bf16x8 __attribute__((ext_vector_type(8)));
typedef float f32x4 __attribute__((ext_vector_type(4)));
typedef float f32x16 __attribute__((ext_vector_type(16)));

__device__ __forceinline__ unsigned short f2b(float f) {
  union { float f; unsigned u; } x; x.f = f;
  return (unsigned short)((x.u + 0x7FFFu + ((x.u >> 16) & 1u)) >> 16);
}
__device__ __forceinline__ float b2f(unsigned short b) {
  union { unsigned u; float f; } x; x.u = ((unsigned)b) << 16;
  return x.f;
}
__device__ __forceinline__ void lds_dma16(void* lds, const void* g) {
  __builtin_amdgcn_global_load_lds(
      (const __attribute__((address_space(1))) unsigned int*)g,
      (__attribute__((address_space(3))) unsigned int*)lds, 16, 0, 0);
}
__device__ __forceinline__ unsigned cvtpk(float lo, float hi) {
  unsigned r;
  asm("v_cvt_pk_bf16_f32 %0, %1, %2" : "=v"(r) : "v"(lo), "v"(hi));
  return r;
}
#define PLSWAP(a, b) asm("v_permlane32_swap_b32 %0, %1" : "+v"(a), "+v"(b))

// redistribute 8 packed u32 (C-layout kv pairs) into two B-frags (k-groups)
__device__ __forceinline__ void redist(unsigned pw[8], bf16x8* f0, bf16x8* f1) {
  PLSWAP(pw[0], pw[2]); PLSWAP(pw[1], pw[3]);
  PLSWAP(pw[4], pw[6]); PLSWAP(pw[5], pw[7]);
  union { unsigned u[4]; bf16x8 v; } a, b;
  a.u[0] = pw[0]; a.u[1] = pw[1]; a.u[2] = pw[2]; a.u[3] = pw[3];
  b.u[0] = pw[4]; b.u[1] = pw[5]; b.u[2] = pw[6]; b.u[3] = pw[7];
  *f0 = a.v; *f1 = b.v;
}

// ---- weight prep: LDS 64x64 tile transposes + Wq bf16 cast ----
// blocks: [0,32) Wk->Wkt | [32,64) Wv->Wvt | [64,192) Wo->Wot | [192,320) Wq cast
__global__ __launch_bounds__(256) void prep_weights(
    const float* __restrict__ Wk, const float* __restrict__ Wv,
    const float* __restrict__ Wo, const float* __restrict__ Wq,
    unsigned short* __restrict__ Wkt, unsigned short* __restrict__ Wvt,
    unsigned short* __restrict__ Wot, unsigned short* __restrict__ Wq2) {
  __shared__ unsigned short T[64][66];
  int b = blockIdx.x, tid = threadIdx.x;
  const float* W;
  unsigned short* D;
  int K, N, tk, tn;
  if (b < 32) {
    W = Wk; D = Wkt; K = 128; N = 1024; int ti = b;       tk = ti & 1;  tn = ti >> 1;
  } else if (b < 64) {
    W = Wv; D = Wvt; K = 128; N = 1024; int ti = b - 32;  tk = ti & 1;  tn = ti >> 1;
  } else if (b < 192) {
    W = Wo; D = Wot; K = 4096; N = 128; int ti = b - 64;  tk = ti >> 1; tn = ti & 1;
  } else {
    int i0 = ((b - 192) * 256 + tid) * 16;  // Wq cast (row-major bf16)
#pragma unroll
    for (int j = 0; j < 16; ++j) Wq2[i0 + j] = f2b(Wq[i0 + j]);
    return;
  }
  int k0 = tk * 64, n0 = tn * 64;
  int c = tid & 63, q = tid >> 6;
#pragma unroll
  for (int i = 0; i < 16; ++i) {
    int r = i * 4 + q;
    T[r][c] = f2b(W[(size_t)(k0 + r) * N + n0 + c]);
  }
  __syncthreads();
#pragma unroll
  for (int i = 0; i < 16; ++i) {
    int r = i * 4 + q;
    D[(size_t)(n0 + r) * K + k0 + c] = T[c][r];
  }
}

// ---- K+V projections with fused RoPE (r12, unchanged semantics) ----
__global__ __launch_bounds__(256) void proj_kv(
    const float* __restrict__ keys, const float* __restrict__ values,
    const unsigned short* __restrict__ Wkt, const unsigned short* __restrict__ Wvt,
    const float* __restrict__ bk, const float* __restrict__ bv,
    unsigned short* __restrict__ kp, unsigned short* __restrict__ vt) {
  int bx = blockIdx.x, m0 = blockIdx.y * 64;
  int tid = threadIdx.x;
  int w = tid >> 6, l = tid & 63;
  int l16 = l & 15, g4 = l >> 4;
  int arow = m0 + w * 16 + l16;
  const f32x4 fz = {0.f, 0.f, 0.f, 0.f};
  int vmode = bx >> 3;
  int n0 = (bx & 7) * 128, tb = bx & 7;
  const float* X = vmode ? values : keys;
  const unsigned short* Wt = vmode ? Wvt : Wkt;
  const float* bias = vmode ? bv : bk;
  f32x4 acc[8];
#pragma unroll
  for (int nb = 0; nb < 8; ++nb) acc[nb] = fz;
#pragma unroll
  for (int kc = 0; kc < 4; ++kc) {
    int kbase = kc * 32 + g4 * 8;
    const float* xp = X + (size_t)arow * 128 + kbase;
    bf16x8 a;
#pragma unroll
    for (int j = 0; j < 8; ++j) a[j] = (short)f2b(xp[j]);
#pragma unroll
    for (int nb = 0; nb < 8; ++nb) {
      bf16x8 b = *(const bf16x8*)(Wt + (size_t)(n0 + nb * 16 + l16) * 128 + kbase);
      acc[nb] = __builtin_amdgcn_mfma_f32_16x16x32_bf16(a, b, acc[nb], 0, 0, 0);
    }
  }
#pragma unroll
  for (int nb = 0; nb < 4; ++nb) {
    int d2 = nb * 16 + l16;
    float invf = exp2f(-(float)d2 * L2_10K_64);
    float blo = bias[n0 + d2], bhi = bias[n0 + d2 + 64];
#pragma unroll
    for (int r = 0; r < 4; ++r) {
      int mi = m0 + w * 16 + g4 * 4 + r;
      int t = (mi & 255) * 8 + tb;
      float ang = (float)t * invf;
      float sf, cf;
      __sincosf(ang, &sf, &cf);
      float x1 = acc[nb][r] + blo;
      float x2 = acc[nb + 4][r] + bhi;
      unsigned short lo = f2b(x1 * cf - x2 * sf);
      unsigned short hi = f2b(x2 * cf + x1 * sf);
      int g = mi >> 8;
      if (vmode) {
        vt[(size_t)g * 262144 + (size_t)d2 * 2048 + t] = lo;
        vt[(size_t)g * 262144 + (size_t)(d2 + 64) * 2048 + t] = hi;
      } else {
        kp[(size_t)g * 262144 + (size_t)t * 128 + d2] = lo;
        kp[(size_t)g * 262144 + (size_t)t * 128 + d2 + 64] = hi;
      }
    }
  }
}

__global__ void ws_marker(float* __restrict__ out) {
  out[blockIdx.x * 256 + threadIdx.x] = 12345.0f;
}

// ---- reduce 8 g-partials + bias -> out ----
__global__ void reduce_out(const float* __restrict__ part, const float* __restrict__ bo,
                           float* __restrict__ out) {
  int idx = blockIdx.x * 256 + threadIdx.x;  // 2048*128
  float s = bo[idx & 127];
#pragma unroll
  for (int g = 0; g < 8; ++g) s += part[(size_t)g * 262144 + idx];
  out[idx] = s;
}

// Grid 512: g = bid&7, q-tile = bid>>3 (32 rows). 4 waves = heads {g,g+8,g+16,g+24}.
// LDS: K[2][64][128]sh @0 (4-bit XOR) | V^T[2][128][64]sh @32768 (3-bit XOR) = 64KB;
// epilogue reuses all 64KB as Psum[4][32][128] f32.
__global__ __launch_bounds__(256, 2) void attn_kernel(
    const float* __restrict__ X, const unsigned short* __restrict__ Wqb,
    const float* __restrict__ bq,
    const unsigned short* __restrict__ kp, const unsigned short* __restrict__ vt,
    const unsigned short* __restrict__ Wot, float* __restrict__ part) {
  __shared__ __align__(16) char smem[65536];
  int bid = blockIdx.x;
  int g = bid & 7;
  int qi0 = (bid >> 3) * 32;
  int q5 = qi0 >> 5;
  int tid = threadIdx.x;
  int w = tid >> 6, l = tid & 63;
  int l31 = l & 31, hi = l >> 5;
  int hw = g + 8 * w;  // this wave's head

  const f32x16 fz16 = {0.f};

  // ---- fused Q-projection: the 4 needed C rows are {(g+8j)*64 + q5}, j=0..3 ----
  {
    unsigned short* Uni = (unsigned short*)smem;  // [4][4096]
    int col0 = tid * 16;
#pragma unroll
    for (int jp = 0; jp < 2; ++jp) {
      float acc[2][16];
#pragma unroll
      for (int j = 0; j < 2; ++j)
#pragma unroll
        for (int cc = 0; cc < 16; ++cc) acc[j][cc] = bq[col0 + cc];
      const float* xr0 = X + (size_t)((g + 8 * (jp * 2)) * 64 + q5) * 128;
      const float* xr1 = X + (size_t)((g + 8 * (jp * 2 + 1)) * 64 + q5) * 128;
      for (int k = 0; k < 128; ++k) {
        float x0 = xr0[k], x1 = xr1[k];
        bf16x8 w0 = *(const bf16x8*)(Wqb + (size_t)k * 4096 + col0);
        bf16x8 w1 = *(const bf16x8*)(Wqb + (size_t)k * 4096 + col0 + 8);
#pragma unroll
        for (int e = 0; e < 8; ++e) {
          float f0 = b2f((unsigned short)w0[e]), f1 = b2f((unsigned short)w1[e]);
          acc[0][e] += x0 * f0; acc[0][8 + e] += x0 * f1;
          acc[1][e] += x1 * f0; acc[1][8 + e] += x1 * f1;
        }
      }
#pragma unroll
      for (int j = 0; j < 2; ++j)
#pragma unroll
        for (int cc = 0; cc < 16; ++cc)
          Uni[(jp * 2 + j) * 4096 + col0 + cc] = f2b(acc[j][cc]);
    }
  }
  __syncthreads();
  bf16x8 qfrag[8];  // wave w's head: row w of Uni; q = l31 within tile
  {
    unsigned short* Uni = (unsigned short*)smem;
#pragma unroll
    for (int kc = 0; kc < 8; ++kc)
      qfrag[kc] = *(const bf16x8*)&Uni[w * 4096 + l31 * 128 + kc * 16 + hi * 8];
  }
  __syncthreads();  // Uni reads done before DMA overwrites region

  const char* kg = (const char*)(kp + (size_t)g * 262144);
  const char* vg = (const char*)(vt + (size_t)g * 262144);

#define STAGE_K(tn, kb)                                                         \
  {                                                                             \
    _Pragma("unroll") for (int i = 0; i < 4; ++i) {                             \
      int off = w * 4096 + i * 1024 + l * 16;                                   \
      int row = off >> 8, ch = (off >> 4) & 15;                                 \
      int rch = ch ^ (row & 15);                                                \
      lds_dma16(smem + (kb) * 16384 + w * 4096 + i * 1024,                      \
                kg + (size_t)(tn) * 16384 + (size_t)row * 256 + rch * 16);      \
    }                                                                           \
  }
#define STAGE_V(tn, vb)                                                         \
  {                                                                             \
    _Pragma("unroll") for (int i = 0; i < 4; ++i) {                             \
      int off = w * 4096 + i * 1024 + l * 16;                                   \
      int row = off >> 7, ch = (off >> 4) & 7;                                  \
      int rch = ch ^ (row & 7);                                                 \
      lds_dma16(smem + 32768 + (vb) * 16384 + w * 4096 + i * 1024,              \
                vg + (size_t)row * 4096 + (size_t)(tn) * 128 + rch * 16);       \
    }                                                                           \
  }

  STAGE_K(0, 0);
  STAGE_V(0, 0);
  __syncthreads();

  f32x16 oacc[4];  // O^T[d][q=l31] for this wave's head
#pragma unroll
  for (int db = 0; db < 4; ++db) oacc[db] = fz16;
  float lacc = 0.f;

  int c = 0;
  for (int t = 0; t < 32; ++t) {
    if (t < 31) { STAGE_K(t + 1, c ^ 1); STAGE_V(t + 1, c ^ 1); }

#pragma unroll
    for (int jb = 0; jb < 2; ++jb) {
      f32x16 sacc = fz16;
      __builtin_amdgcn_s_setprio(1);
#pragma unroll
      for (int kc = 0; kc < 8; ++kc) {
        int row = jb * 32 + l31;
        int rch = (kc * 2 + hi) ^ (row & 15);
        bf16x8 kfrag = *(const bf16x8*)(smem + c * 16384 + row * 256 + rch * 16);
        sacc = __builtin_amdgcn_mfma_f32_32x32x16_bf16(kfrag, qfrag[kc], sacc, 0, 0, 0);
      }
      __builtin_amdgcn_s_setprio(0);
      float p[16];
#pragma unroll
      for (int j = 0; j < 16; ++j) {
        p[j] = exp2f(sacc[j] * SCALE_L2E);
        lacc += p[j];
      }
      unsigned pw[8];
#pragma unroll
      for (int m = 0; m < 8; ++m) pw[m] = cvtpk(p[2 * m], p[2 * m + 1]);
      bf16x8 pf0, pf1;
      redist(pw, &pf0, &pf1);
      __builtin_amdgcn_s_setprio(1);
#pragma unroll
      for (int ks = 0; ks < 2; ++ks) {
        int ksg = jb * 2 + ks;
        bf16x8 pf = ks ? pf1 : pf0;
#pragma unroll
        for (int db = 0; db < 4; ++db) {
          int row = db * 32 + l31;
          int rch = (ksg * 2 + hi) ^ (row & 7);
          bf16x8 vfrag = *(const bf16x8*)(smem + 32768 + c * 16384 + row * 128 + rch * 16);
          oacc[db] = __builtin_amdgcn_mfma_f32_32x32x16_bf16(vfrag, pf, oacc[db], 0, 0, 0);
        }
      }
      __builtin_amdgcn_s_setprio(0);
    }
    __syncthreads();
    c ^= 1;
  }

  float ltot = lacc + __shfl_xor(lacc, 32, 64);
  float invl = 1.f / ltot;

  // ---- epilogue: per-wave O@Wo (in-register redist), LDS sum over 4 heads,
  //      plain stores to part[g] (exclusive writer) ----
  f32x16 acc2[4];
#pragma unroll
  for (int nb = 0; nb < 4; ++nb) acc2[nb] = fz16;
  bf16x8 ofrag[8];
#pragma unroll
  for (int db = 0; db < 4; ++db) {
    unsigned pw[8];
#pragma unroll
    for (int m = 0; m < 8; ++m)
      pw[m] = cvtpk(oacc[db][2 * m] * invl, oacc[db][2 * m + 1] * invl);
    redist(pw, &ofrag[db * 2], &ofrag[db * 2 + 1]);
  }
#pragma unroll
  for (int ks = 0; ks < 8; ++ks) {
#pragma unroll
    for (int nb = 0; nb < 4; ++nb) {
      bf16x8 wof = *(const bf16x8*)(Wot + (size_t)(nb * 32 + l31) * 4096 + hw * 128 + ks * 16 + hi * 8);
      acc2[nb] = __builtin_amdgcn_mfma_f32_32x32x16_bf16(wof, ofrag[ks], acc2[nb], 0, 0, 0);
    }
  }
  __syncthreads();  // loop reads of smem done everywhere; reuse as Psum[4][32][128] f32
  float* Psum = (float*)(smem + w * 16384);
#pragma unroll
  for (int nb = 0; nb < 4; ++nb) {
#pragma unroll
    for (int j = 0; j < 16; ++j) {
      int no = nb * 32 + (j & 3) + 8 * (j >> 2) + 4 * hi;
      Psum[l31 * 128 + no] = acc2[nb][j];
    }
  }
  __syncthreads();
  {
    float* P0 = (float*)smem;
    float* dst = part + (size_t)g * 262144 + (size_t)qi0 * 128;
#pragma unroll
    for (int i = 0; i < 16; ++i) {
      int cidx = i * 256 + tid;  // cidx = q*128 + no, coalesced
      dst[cidx] = P0[cidx] + P0[4096 + cidx] + P0[8192 + cidx] + P0[12288 + cidx];
    }
  }
#undef STAGE_K
#undef STAGE_V
}

extern "C" void kernel_launch(void* const* d_in, const int* in_sizes, int n_in,
                              void* d_out, int out_size, void* d_ws, size_t ws_size,
                              hipStream_t stream) {
  const float* query  = (const float*)d_in[0];
  const float* keys   = (const float*)d_in[1];
  const float* values = (const float*)d_in[2];
  const float* Wq = (const float*)d_in[3];
  const float* bq = (const float*)d_in[4];
  const float* Wk = (const float*)d_in[5];
  const float* bk = (const float*)d_in[6];
  const float* Wv = (const float*)d_in[7];
  const float* bv = (const float*)d_in[8];
  const float* Wo = (const float*)d_in[9];
  const float* bo = (const float*)d_in[10];
  float* out = (float*)d_out;
  char* ws = (char*)d_ws;
  const size_t MB = 1024 * 1024;
  const size_t NEED = 18 * MB + 512 * 1024;  // 18.5 MB
  if (ws_size < NEED) {  // sentinel: absmax 12345 => ws too small
    ws_marker<<<1024, 256, 0, stream>>>(out);
    return;
  }
  unsigned short* Wq2   = (unsigned short*)(ws);                        // 1 MiB
  unsigned short* Wkt   = (unsigned short*)(ws + 1 * MB);               // 256 KiB
  unsigned short* Wvt   = (unsigned short*)(ws + 1 * MB + 256 * 1024);  // 256 KiB
  unsigned short* Wot   = (unsigned short*)(ws + 1 * MB + 512 * 1024);  // 1 MiB
  unsigned short* kproj = (unsigned short*)(ws + 2 * MB + 512 * 1024);  // 4 MiB
  unsigned short* vt    = (unsigned short*)(ws + 6 * MB + 512 * 1024);  // 4 MiB
  float* part           = (float*)(ws + 10 * MB + 512 * 1024);          // 8 MiB -> 18.5

  prep_weights<<<320, 256, 0, stream>>>(Wk, Wv, Wo, Wq, Wkt, Wvt, Wot, Wq2);
  proj_kv<<<dim3(16, 32), 256, 0, stream>>>(keys, values, Wkt, Wvt, bk, bv, kproj, vt);
  attn_kernel<<<512, 256, 0, stream>>>(query, Wq2, bq, kproj, vt, Wot, part);
  reduce_out<<<1024, 256, 0, stream>>>(part, bo, out);
}